// Round 1
// baseline (91.137 us; speedup 1.0000x reference)
//
#include <hip/hip_runtime.h>
#include <hip/hip_bf16.h>
#include <math.h>

// Problem constants (fixed by the reference's setup_inputs)
#define N_STATE 1024
#define N_HEAD  16
#define H_DIM   64          // N_STATE / N_HEAD
#define NUM_ROT 8
#define SEQ     4096

// ---------------------------------------------------------------------------
// Kernel 1: compose the 64x64 rotation matrix
//   R = G_0 @ G_1 @ ... @ G_7 @ rotation_matrix
// Each G_k differs from identity only in columns i,j, so R@G_k is a column op:
//   newcol_i =  c*col_i + s*col_j ; newcol_j = -s*col_i + c*col_j
// i==j corner case (reference's chained .at sets): G[i,i] ends at c -> col_i *= c.
// 1 block, 256 threads: thread t owns row r=t>>2, 16 cols (t&3)*16.. .
// ---------------------------------------------------------------------------
__global__ void compose_R_kernel(const float* __restrict__ thetas,
                                 const float* __restrict__ pairs,
                                 const float* __restrict__ theta_scale,
                                 const float* __restrict__ M,
                                 float* __restrict__ Rout)
{
    __shared__ float R[H_DIM * H_DIM];
    const int t  = threadIdx.x;
    const int r  = t >> 2;
    const int cq = t & 3;

    #pragma unroll
    for (int k = 0; k < 16; ++k) {
        const int c = cq * 16 + k;
        R[r * H_DIM + c] = (r == c) ? 1.0f : 0.0f;
    }
    __syncthreads();

    const float ts = theta_scale[0];
    for (int k = 0; k < NUM_ROT; ++k) {
        const int i = (int)pairs[2 * k];
        const int j = (int)pairs[2 * k + 1];
        float sth, cth;
        sincosf(thetas[k] * ts, &sth, &cth);
        const float ri = R[r * H_DIM + i];
        const float rj = R[r * H_DIM + j];
        __syncthreads();
        if (cq == 0) {
            if (i == j) {
                R[r * H_DIM + i] = cth * ri;
            } else {
                R[r * H_DIM + i] =  cth * ri + sth * rj;
                R[r * H_DIM + j] = -sth * ri + cth * rj;
            }
        }
        __syncthreads();
    }

    // Rout = R @ M
    #pragma unroll
    for (int k2 = 0; k2 < 16; ++k2) {
        const int c = cq * 16 + k2;
        float acc = 0.0f;
        for (int kk = 0; kk < H_DIM; ++kk)
            acc = fmaf(R[r * H_DIM + kk], M[kk * H_DIM + c], acc);
        Rout[r * H_DIM + c] = acc;
    }
}

// ---------------------------------------------------------------------------
// Kernel 2: main fused kernel.
// Block = 256 threads, handles HVPB=128 head-vectors (= 8 sequence rows).
//  - stage R (16KB) into LDS
//  - compute sin/cos for the block's 8 rows x 32 freqs (1 sincosf/thread)
//  - stage x tile (128x64 f32, LDS stride 68 to limit bank aliasing)
//  - each thread: 4 hv x 8 cols register tile, K=64 fp32 FMA loop
//  - fused RoPE epilogue, coalesced float4 stores
// ---------------------------------------------------------------------------
#define HVPB 128
#define XS_STRIDE 68

__global__ __launch_bounds__(256)
void rope_main_kernel(const float* __restrict__ x,
                      const float* __restrict__ Rg,
                      const float* __restrict__ inv_freq,
                      float* __restrict__ out)
{
    __shared__ float Rs[H_DIM * H_DIM];          // 16384 B
    __shared__ float xs[HVPB * XS_STRIDE];       // 34816 B
    __shared__ float snc[8 * 64];                // 2048 B: [row][0..31]=sin, [32..63]=cos

    const int t = threadIdx.x;
    const long long hv_base = (long long)blockIdx.x * HVPB;
    const int row_base = (int)(hv_base >> 4);    // 16 head-vectors per (b,s) row

    // --- stage R ---
    {
        const float4* Rg4 = reinterpret_cast<const float4*>(Rg);
        float4* Rs4 = reinterpret_cast<float4*>(Rs);
        #pragma unroll
        for (int q = 0; q < 4; ++q)
            Rs4[t + q * 256] = Rg4[t + q * 256];
    }

    // --- sin/cos for this block's 8 rows ---
    {
        const int rl = t >> 5;          // 0..7
        const int f  = t & 31;          // 0..31
        const int s_idx = (row_base + rl) & (SEQ - 1);
        float sv, cv;
        sincosf((float)s_idx * inv_freq[f], &sv, &cv);
        snc[rl * 64 + f]      = sv;
        snc[rl * 64 + 32 + f] = cv;
    }

    // --- stage x tile: 2048 float4, 8 per thread, coalesced ---
    {
        const float4* xg = reinterpret_cast<const float4*>(x + hv_base * H_DIM);
        #pragma unroll
        for (int k = 0; k < 8; ++k) {
            const int p = t + k * 256;           // 0..2047
            const int hv_l = p >> 4;             // 0..127
            const int r4   = p & 15;             // float4 index within row
            *reinterpret_cast<float4*>(&xs[hv_l * XS_STRIDE + r4 * 4]) = xg[p];
        }
    }

    __syncthreads();

    // --- register-tile matmul: thread = 4 hv x 8 cols ---
    const int cg = t & 7;     // column group: cols cg*8 .. cg*8+7
    const int hg = t >> 3;    // hv group: hvs hg*4 .. hg*4+3

    float acc[4][8];
    #pragma unroll
    for (int i = 0; i < 4; ++i)
        #pragma unroll
        for (int c = 0; c < 8; ++c)
            acc[i][c] = 0.0f;

    const float4* Rv = reinterpret_cast<const float4*>(Rs);

    for (int rq = 0; rq < 16; ++rq) {
        float4 xq4[4];
        #pragma unroll
        for (int i = 0; i < 4; ++i)
            xq4[i] = *reinterpret_cast<const float4*>(
                &xs[(hg * 4 + i) * XS_STRIDE + rq * 4]);

        #pragma unroll
        for (int rr = 0; rr < 4; ++rr) {
            const int r = rq * 4 + rr;
            const float4 b0 = Rv[r * 16 + cg * 2];
            const float4 b1 = Rv[r * 16 + cg * 2 + 1];
            #pragma unroll
            for (int i = 0; i < 4; ++i) {
                const float xv = (rr == 0) ? xq4[i].x :
                                 (rr == 1) ? xq4[i].y :
                                 (rr == 2) ? xq4[i].z : xq4[i].w;
                acc[i][0] = fmaf(xv, b0.x, acc[i][0]);
                acc[i][1] = fmaf(xv, b0.y, acc[i][1]);
                acc[i][2] = fmaf(xv, b0.z, acc[i][2]);
                acc[i][3] = fmaf(xv, b0.w, acc[i][3]);
                acc[i][4] = fmaf(xv, b1.x, acc[i][4]);
                acc[i][5] = fmaf(xv, b1.y, acc[i][5]);
                acc[i][6] = fmaf(xv, b1.z, acc[i][6]);
                acc[i][7] = fmaf(xv, b1.w, acc[i][7]);
            }
        }
    }

    // --- fused RoPE epilogue + store ---
    // Thread's 8 cols are pairs (2f, 2f+1) for f = cg*4 .. cg*4+3.
    // out[..,f] = y[2f]*cos - y[2f+1]*sin ; out[..,32+f] = y[2f]*sin + y[2f+1]*cos
    const int rl = hg >> 2;
    const float4 sn = *reinterpret_cast<const float4*>(&snc[rl * 64 + cg * 4]);
    const float4 cs = *reinterpret_cast<const float4*>(&snc[rl * 64 + 32 + cg * 4]);

    #pragma unroll
    for (int i = 0; i < 4; ++i) {
        const long long hv = hv_base + hg * 4 + i;
        float4 o1, o2;
        o1.x = acc[i][0] * cs.x - acc[i][1] * sn.x;
        o2.x = acc[i][0] * sn.x + acc[i][1] * cs.x;
        o1.y = acc[i][2] * cs.y - acc[i][3] * sn.y;
        o2.y = acc[i][2] * sn.y + acc[i][3] * cs.y;
        o1.z = acc[i][4] * cs.z - acc[i][5] * sn.z;
        o2.z = acc[i][4] * sn.z + acc[i][5] * cs.z;
        o1.w = acc[i][6] * cs.w - acc[i][7] * sn.w;
        o2.w = acc[i][6] * sn.w + acc[i][7] * cs.w;
        float4* op = reinterpret_cast<float4*>(out + hv * H_DIM);
        op[cg]     = o1;   // cols cg*4 .. cg*4+3        (first half)
        op[8 + cg] = o2;   // cols 32+cg*4 .. 32+cg*4+3  (second half)
    }
}

// ---------------------------------------------------------------------------
extern "C" void kernel_launch(void* const* d_in, const int* in_sizes, int n_in,
                              void* d_out, int out_size, void* d_ws, size_t ws_size,
                              hipStream_t stream)
{
    const float* x      = (const float*)d_in[0];
    const float* thetas = (const float*)d_in[1];
    const float* pairs  = (const float*)d_in[2];
    const float* tscale = (const float*)d_in[3];
    const float* M      = (const float*)d_in[4];
    const float* invf   = (const float*)d_in[5];
    float* out = (float*)d_out;
    float* Rws = (float*)d_ws;   // 64*64 floats = 16 KiB scratch for composed R

    compose_R_kernel<<<1, 256, 0, stream>>>(thetas, pairs, tscale, M, Rws);

    const int n_hv   = in_sizes[0] / H_DIM;     // B*S*N_HEAD = 262144
    const int blocks = n_hv / HVPB;             // 2048
    rope_main_kernel<<<blocks, 256, 0, stream>>>(x, Rws, invf, out);
}

// Round 2
// 47.947 us; speedup vs baseline: 1.9008x; 1.9008x over previous
//
#include <hip/hip_runtime.h>
#include <hip/hip_bf16.h>
#include <math.h>

// Problem constants (fixed by the reference's setup_inputs)
#define N_STATE 1024
#define N_HEAD  16
#define H_DIM   64          // N_STATE / N_HEAD
#define NUM_ROT 8
#define SEQ     4096

// ---------------------------------------------------------------------------
// Kernel 1: compose the 64x64 rotation matrix
//   R = G_0 @ G_1 @ ... @ G_7 @ rotation_matrix
// R@G_k is a column op on cols i,j:
//   newcol_i =  c*col_i + s*col_j ; newcol_j = -s*col_i + c*col_j
// i==j corner (reference's chained .at): G[i,i] ends at c -> col_i *= c.
//
// Round-2 rewrite: the 64us cost was latency-serialized scalar global loads
// of M inside the dependent FMA chain (1 block, no TLP). Now: M staged to LDS
// via coalesced float4, thetas/pairs preloaded once, matmul register-tiled
// from LDS. Expected ~3us.
// ---------------------------------------------------------------------------
__global__ __launch_bounds__(256)
void compose_R_kernel(const float* __restrict__ thetas,
                      const float* __restrict__ pairs,
                      const float* __restrict__ theta_scale,
                      const float* __restrict__ M,
                      float* __restrict__ Rout)
{
    __shared__ float R[H_DIM * H_DIM];     // 16 KiB
    __shared__ float Ms[H_DIM * H_DIM];    // 16 KiB
    __shared__ float th_s[NUM_ROT];
    __shared__ int   pr_s[2 * NUM_ROT];

    const int t = threadIdx.x;

    // --- preload small params (one-shot latency) ---
    if (t < NUM_ROT)      th_s[t] = thetas[t] * theta_scale[0];
    if (t < 2 * NUM_ROT)  pr_s[t] = (int)pairs[t];

    // --- stage M coalesced: 1024 float4, 4 per thread ---
    {
        const float4* Mg = reinterpret_cast<const float4*>(M);
        float4* Ms4 = reinterpret_cast<float4*>(Ms);
        #pragma unroll
        for (int q = 0; q < 4; ++q)
            Ms4[t + q * 256] = Mg[t + q * 256];
    }

    // --- init R = I ---
    {
        float4* R4 = reinterpret_cast<float4*>(R);
        #pragma unroll
        for (int q = 0; q < 4; ++q) {
            const int idx = t + q * 256;        // float4 index
            const int row = idx >> 4;
            const int c0  = (idx & 15) * 4;
            float4 v;
            v.x = (row == c0    ) ? 1.0f : 0.0f;
            v.y = (row == c0 + 1) ? 1.0f : 0.0f;
            v.z = (row == c0 + 2) ? 1.0f : 0.0f;
            v.w = (row == c0 + 3) ? 1.0f : 0.0f;
            R4[idx] = v;
        }
    }
    __syncthreads();

    // --- 8 Givens column ops; threads 0..63 each own one row of R ---
    for (int k = 0; k < NUM_ROT; ++k) {
        const int i = pr_s[2 * k];
        const int j = pr_s[2 * k + 1];
        float sth, cth;
        sincosf(th_s[k], &sth, &cth);
        if (t < H_DIM) {
            const float ri = R[t * H_DIM + i];
            const float rj = R[t * H_DIM + j];
            if (i == j) {
                R[t * H_DIM + i] = cth * ri;
            } else {
                R[t * H_DIM + i] =  cth * ri + sth * rj;
                R[t * H_DIM + j] = -sth * ri + cth * rj;
            }
        }
        __syncthreads();
    }

    // --- Rout = R @ Ms: thread t -> row r=t>>2, cols (t&3)*16 .. +15 ---
    const int r  = t >> 2;
    const int c0 = (t & 3) * 16;
    float acc[16];
    #pragma unroll
    for (int c = 0; c < 16; ++c) acc[c] = 0.0f;

    #pragma unroll 8
    for (int kk = 0; kk < H_DIM; ++kk) {
        const float a = R[r * H_DIM + kk];
        const float4* mrow = reinterpret_cast<const float4*>(&Ms[kk * H_DIM + c0]);
        #pragma unroll
        for (int c4 = 0; c4 < 4; ++c4) {
            const float4 m = mrow[c4];
            acc[c4 * 4 + 0] = fmaf(a, m.x, acc[c4 * 4 + 0]);
            acc[c4 * 4 + 1] = fmaf(a, m.y, acc[c4 * 4 + 1]);
            acc[c4 * 4 + 2] = fmaf(a, m.z, acc[c4 * 4 + 2]);
            acc[c4 * 4 + 3] = fmaf(a, m.w, acc[c4 * 4 + 3]);
        }
    }

    #pragma unroll
    for (int c4 = 0; c4 < 4; ++c4) {
        float4 v;
        v.x = acc[c4 * 4 + 0];
        v.y = acc[c4 * 4 + 1];
        v.z = acc[c4 * 4 + 2];
        v.w = acc[c4 * 4 + 3];
        *reinterpret_cast<float4*>(&Rout[r * H_DIM + c0 + c4 * 4]) = v;
    }
}

// ---------------------------------------------------------------------------
// Kernel 2: main fused kernel (unchanged from round 1 — ~27us, ~5 TB/s).
// Block = 256 threads, handles HVPB=128 head-vectors (= 8 sequence rows).
// ---------------------------------------------------------------------------
#define HVPB 128
#define XS_STRIDE 68

__global__ __launch_bounds__(256)
void rope_main_kernel(const float* __restrict__ x,
                      const float* __restrict__ Rg,
                      const float* __restrict__ inv_freq,
                      float* __restrict__ out)
{
    __shared__ float Rs[H_DIM * H_DIM];          // 16384 B
    __shared__ float xs[HVPB * XS_STRIDE];       // 34816 B
    __shared__ float snc[8 * 64];                // 2048 B: [row][0..31]=sin, [32..63]=cos

    const int t = threadIdx.x;
    const long long hv_base = (long long)blockIdx.x * HVPB;
    const int row_base = (int)(hv_base >> 4);    // 16 head-vectors per (b,s) row

    // --- stage R ---
    {
        const float4* Rg4 = reinterpret_cast<const float4*>(Rg);
        float4* Rs4 = reinterpret_cast<float4*>(Rs);
        #pragma unroll
        for (int q = 0; q < 4; ++q)
            Rs4[t + q * 256] = Rg4[t + q * 256];
    }

    // --- sin/cos for this block's 8 rows ---
    {
        const int rl = t >> 5;          // 0..7
        const int f  = t & 31;          // 0..31
        const int s_idx = (row_base + rl) & (SEQ - 1);
        float sv, cv;
        sincosf((float)s_idx * inv_freq[f], &sv, &cv);
        snc[rl * 64 + f]      = sv;
        snc[rl * 64 + 32 + f] = cv;
    }

    // --- stage x tile: 2048 float4, 8 per thread, coalesced ---
    {
        const float4* xg = reinterpret_cast<const float4*>(x + hv_base * H_DIM);
        #pragma unroll
        for (int k = 0; k < 8; ++k) {
            const int p = t + k * 256;           // 0..2047
            const int hv_l = p >> 4;             // 0..127
            const int r4   = p & 15;             // float4 index within row
            *reinterpret_cast<float4*>(&xs[hv_l * XS_STRIDE + r4 * 4]) = xg[p];
        }
    }

    __syncthreads();

    // --- register-tile matmul: thread = 4 hv x 8 cols ---
    const int cg = t & 7;     // column group: cols cg*8 .. cg*8+7
    const int hg = t >> 3;    // hv group: hvs hg*4 .. hg*4+3

    float acc[4][8];
    #pragma unroll
    for (int i = 0; i < 4; ++i)
        #pragma unroll
        for (int c = 0; c < 8; ++c)
            acc[i][c] = 0.0f;

    const float4* Rv = reinterpret_cast<const float4*>(Rs);

    for (int rq = 0; rq < 16; ++rq) {
        float4 xq4[4];
        #pragma unroll
        for (int i = 0; i < 4; ++i)
            xq4[i] = *reinterpret_cast<const float4*>(
                &xs[(hg * 4 + i) * XS_STRIDE + rq * 4]);

        #pragma unroll
        for (int rr = 0; rr < 4; ++rr) {
            const int r = rq * 4 + rr;
            const float4 b0 = Rv[r * 16 + cg * 2];
            const float4 b1 = Rv[r * 16 + cg * 2 + 1];
            #pragma unroll
            for (int i = 0; i < 4; ++i) {
                const float xv = (rr == 0) ? xq4[i].x :
                                 (rr == 1) ? xq4[i].y :
                                 (rr == 2) ? xq4[i].z : xq4[i].w;
                acc[i][0] = fmaf(xv, b0.x, acc[i][0]);
                acc[i][1] = fmaf(xv, b0.y, acc[i][1]);
                acc[i][2] = fmaf(xv, b0.z, acc[i][2]);
                acc[i][3] = fmaf(xv, b0.w, acc[i][3]);
                acc[i][4] = fmaf(xv, b1.x, acc[i][4]);
                acc[i][5] = fmaf(xv, b1.y, acc[i][5]);
                acc[i][6] = fmaf(xv, b1.z, acc[i][6]);
                acc[i][7] = fmaf(xv, b1.w, acc[i][7]);
            }
        }
    }

    // --- fused RoPE epilogue + store ---
    // Thread's 8 cols are pairs (2f, 2f+1) for f = cg*4 .. cg*4+3.
    // out[..,f] = y[2f]*cos - y[2f+1]*sin ; out[..,32+f] = y[2f]*sin + y[2f+1]*cos
    const int rl = hg >> 2;
    const float4 sn = *reinterpret_cast<const float4*>(&snc[rl * 64 + cg * 4]);
    const float4 cs = *reinterpret_cast<const float4*>(&snc[rl * 64 + 32 + cg * 4]);

    #pragma unroll
    for (int i = 0; i < 4; ++i) {
        const long long hv = hv_base + hg * 4 + i;
        float4 o1, o2;
        o1.x = acc[i][0] * cs.x - acc[i][1] * sn.x;
        o2.x = acc[i][0] * sn.x + acc[i][1] * cs.x;
        o1.y = acc[i][2] * cs.y - acc[i][3] * sn.y;
        o2.y = acc[i][2] * sn.y + acc[i][3] * cs.y;
        o1.z = acc[i][4] * cs.z - acc[i][5] * sn.z;
        o2.z = acc[i][4] * sn.z + acc[i][5] * cs.z;
        o1.w = acc[i][6] * cs.w - acc[i][7] * sn.w;
        o2.w = acc[i][6] * sn.w + acc[i][7] * cs.w;
        float4* op = reinterpret_cast<float4*>(out + hv * H_DIM);
        op[cg]     = o1;   // cols cg*4 .. cg*4+3        (first half)
        op[8 + cg] = o2;   // cols 32+cg*4 .. 32+cg*4+3  (second half)
    }
}

// ---------------------------------------------------------------------------
extern "C" void kernel_launch(void* const* d_in, const int* in_sizes, int n_in,
                              void* d_out, int out_size, void* d_ws, size_t ws_size,
                              hipStream_t stream)
{
    const float* x      = (const float*)d_in[0];
    const float* thetas = (const float*)d_in[1];
    const float* pairs  = (const float*)d_in[2];
    const float* tscale = (const float*)d_in[3];
    const float* M      = (const float*)d_in[4];
    const float* invf   = (const float*)d_in[5];
    float* out = (float*)d_out;
    float* Rws = (float*)d_ws;   // 64*64 floats = 16 KiB scratch for composed R

    compose_R_kernel<<<1, 256, 0, stream>>>(thetas, pairs, tscale, M, Rws);

    const int n_hv   = in_sizes[0] / H_DIM;     // B*S*N_HEAD = 262144
    const int blocks = n_hv / HVPB;             // 2048
    rope_main_kernel<<<blocks, 256, 0, stream>>>(x, Rws, invf, out);
}

// Round 3
// 44.792 us; speedup vs baseline: 2.0347x; 1.0704x over previous
//
#include <hip/hip_runtime.h>
#include <hip/hip_bf16.h>
#include <math.h>

// Problem constants (fixed by the reference's setup_inputs)
#define N_STATE 1024
#define N_HEAD  16
#define H_DIM   64          // N_STATE / N_HEAD
#define NUM_ROT 8
#define SEQ     4096

typedef __attribute__((ext_vector_type(8))) short bf16x8;
typedef __attribute__((ext_vector_type(4))) float f32x4;

// float -> bf16 (round-to-nearest-even)
__device__ __forceinline__ unsigned short f2bf(float f) {
    union { float f; unsigned u; } v; v.f = f;
    unsigned r = v.u + 0x7fffu + ((v.u >> 16) & 1u);
    return (unsigned short)(r >> 16);
}

// ---------------------------------------------------------------------------
// Kernel 1: compose R = G_0 @ ... @ G_7 @ rotation_matrix, then emit
// R^T in bf16 (Rt[m][k] = R[k][m]) for the MFMA main kernel's A operand.
// M staged to LDS (round-2 fix for the 64us latency pathology).
// ---------------------------------------------------------------------------
__global__ __launch_bounds__(256)
void compose_R_kernel(const float* __restrict__ thetas,
                      const float* __restrict__ pairs,
                      const float* __restrict__ theta_scale,
                      const float* __restrict__ M,
                      unsigned short* __restrict__ Rt)   // bf16 [64 m][64 k]
{
    __shared__ float R[H_DIM * H_DIM];     // 16 KiB
    __shared__ float Ms[H_DIM * H_DIM];    // 16 KiB
    __shared__ float th_s[NUM_ROT];
    __shared__ int   pr_s[2 * NUM_ROT];

    const int t = threadIdx.x;

    if (t < NUM_ROT)      th_s[t] = thetas[t] * theta_scale[0];
    if (t < 2 * NUM_ROT)  pr_s[t] = (int)pairs[t];

    // stage M coalesced
    {
        const float4* Mg = reinterpret_cast<const float4*>(M);
        float4* Ms4 = reinterpret_cast<float4*>(Ms);
        #pragma unroll
        for (int q = 0; q < 4; ++q)
            Ms4[t + q * 256] = Mg[t + q * 256];
    }

    // init R = I
    {
        float4* R4 = reinterpret_cast<float4*>(R);
        #pragma unroll
        for (int q = 0; q < 4; ++q) {
            const int idx = t + q * 256;
            const int row = idx >> 4;
            const int c0  = (idx & 15) * 4;
            float4 v;
            v.x = (row == c0    ) ? 1.0f : 0.0f;
            v.y = (row == c0 + 1) ? 1.0f : 0.0f;
            v.z = (row == c0 + 2) ? 1.0f : 0.0f;
            v.w = (row == c0 + 3) ? 1.0f : 0.0f;
            R4[idx] = v;
        }
    }
    __syncthreads();

    // 8 Givens column ops (threads 0..63 own one row each)
    for (int k = 0; k < NUM_ROT; ++k) {
        const int i = pr_s[2 * k];
        const int j = pr_s[2 * k + 1];
        float sth, cth;
        sincosf(th_s[k], &sth, &cth);
        if (t < H_DIM) {
            const float ri = R[t * H_DIM + i];
            const float rj = R[t * H_DIM + j];
            if (i == j) {
                R[t * H_DIM + i] = cth * ri;
            } else {
                R[t * H_DIM + i] =  cth * ri + sth * rj;
                R[t * H_DIM + j] = -sth * ri + cth * rj;
            }
        }
        __syncthreads();
    }

    // Rfinal = R @ Ms ; store transposed bf16: Rt[c][r] = Rfinal[r][c]
    const int r  = t >> 2;
    const int c0 = (t & 3) * 16;
    float acc[16];
    #pragma unroll
    for (int c = 0; c < 16; ++c) acc[c] = 0.0f;

    #pragma unroll 8
    for (int kk = 0; kk < H_DIM; ++kk) {
        const float a = R[r * H_DIM + kk];
        const float4* mrow = reinterpret_cast<const float4*>(&Ms[kk * H_DIM + c0]);
        #pragma unroll
        for (int c4 = 0; c4 < 4; ++c4) {
            const float4 m = mrow[c4];
            acc[c4 * 4 + 0] = fmaf(a, m.x, acc[c4 * 4 + 0]);
            acc[c4 * 4 + 1] = fmaf(a, m.y, acc[c4 * 4 + 1]);
            acc[c4 * 4 + 2] = fmaf(a, m.z, acc[c4 * 4 + 2]);
            acc[c4 * 4 + 3] = fmaf(a, m.w, acc[c4 * 4 + 3]);
        }
    }

    #pragma unroll
    for (int c = 0; c < 16; ++c)
        Rt[(c0 + c) * H_DIM + r] = f2bf(acc[c]);
}

// ---------------------------------------------------------------------------
// Kernel 2: MFMA main kernel.
// Block = 256 threads (4 waves), 128 head-vectors (= 8 sequence positions).
// Computes D = A*B with A = R^T (bf16, 64 features x 64 k, from global/L2)
// and B = x^T (bf16-converted in reg; B-frag reads are contiguous along K in
// row-major x). D-frag rows = output features -> RoPE pairs (2f,2f+1) are
// lane-local adjacent acc regs. LDS = 2KB sin/cos only; one barrier.
// ---------------------------------------------------------------------------
__global__ __launch_bounds__(256, 4)
void rope_mfma_kernel(const float* __restrict__ x,
                      const unsigned short* __restrict__ Rt,  // bf16 [64][64]
                      const float* __restrict__ inv_freq,
                      float* __restrict__ out)
{
    __shared__ float snc[8 * 64];   // [pos][0..31]=sin, [32..63]=cos

    const int t   = threadIdx.x;
    const int w   = t >> 6;          // wave 0..3
    const int l   = t & 63;
    const int r16 = l & 15;
    const int q4  = l >> 4;          // 0..3
    const long long hv_base = (long long)blockIdx.x * 128;

    // --- issue x loads (B operand): 2 n-tiles x 2 k-halves x 8 f32 ---
    float4 xv[2][2][2];
    #pragma unroll
    for (int nt = 0; nt < 2; ++nt) {
        const size_t row = (size_t)(hv_base + w * 32 + nt * 16 + r16);
        const float* rp = x + row * H_DIM;
        #pragma unroll
        for (int kh = 0; kh < 2; ++kh) {
            const float4* p = reinterpret_cast<const float4*>(rp + kh * 32 + q4 * 8);
            xv[nt][kh][0] = p[0];
            xv[nt][kh][1] = p[1];
        }
    }

    // --- A frags straight from bf16 R^T (L2-hot, 8KB shared by all blocks) ---
    bf16x8 afr[4][2];
    #pragma unroll
    for (int mt = 0; mt < 4; ++mt) {
        #pragma unroll
        for (int kh = 0; kh < 2; ++kh) {
            const int m = mt * 16 + r16;
            afr[mt][kh] = *reinterpret_cast<const bf16x8*>(
                Rt + m * H_DIM + kh * 32 + q4 * 8);
        }
    }

    // --- sin/cos table for this block's 8 positions (1 sincosf/thread) ---
    {
        const int rl = t >> 5;          // 0..7
        const int f  = t & 31;          // 0..31
        const int pos = (int)(((hv_base >> 4) + rl) & (SEQ - 1));
        float sv, cv;
        sincosf((float)pos * inv_freq[f], &sv, &cv);
        snc[rl * 64 + f]      = sv;
        snc[rl * 64 + 32 + f] = cv;
    }

    // --- convert x to bf16 B-frags ---
    bf16x8 bfr[2][2];
    #pragma unroll
    for (int nt = 0; nt < 2; ++nt) {
        #pragma unroll
        for (int kh = 0; kh < 2; ++kh) {
            bf16x8 b;
            b[0] = (short)f2bf(xv[nt][kh][0].x);
            b[1] = (short)f2bf(xv[nt][kh][0].y);
            b[2] = (short)f2bf(xv[nt][kh][0].z);
            b[3] = (short)f2bf(xv[nt][kh][0].w);
            b[4] = (short)f2bf(xv[nt][kh][1].x);
            b[5] = (short)f2bf(xv[nt][kh][1].y);
            b[6] = (short)f2bf(xv[nt][kh][1].z);
            b[7] = (short)f2bf(xv[nt][kh][1].w);
            bfr[nt][kh] = b;
        }
    }

    // --- MFMA: D[feature][xrow], 2 nt x 4 mt tiles, K=64 in 2 halves ---
    f32x4 acc[2][4];
    #pragma unroll
    for (int nt = 0; nt < 2; ++nt)
        #pragma unroll
        for (int mt = 0; mt < 4; ++mt) {
            f32x4 z = {0.0f, 0.0f, 0.0f, 0.0f};
            z = __builtin_amdgcn_mfma_f32_16x16x32_bf16(afr[mt][0], bfr[nt][0], z, 0, 0, 0);
            z = __builtin_amdgcn_mfma_f32_16x16x32_bf16(afr[mt][1], bfr[nt][1], z, 0, 0, 0);
            acc[nt][mt] = z;
        }

    __syncthreads();   // snc ready

    // --- RoPE epilogue: lane-local pairs, float2 stores ---
    #pragma unroll
    for (int nt = 0; nt < 2; ++nt) {
        const int pl = w * 2 + nt;                       // block-local position
        const size_t row = (size_t)(hv_base + w * 32 + nt * 16 + r16);
        float* op = out + row * H_DIM;
        #pragma unroll
        for (int mt = 0; mt < 4; ++mt) {
            const int f0 = mt * 8 + q4 * 2;              // even, 0..30
            const float2 sn = *reinterpret_cast<const float2*>(&snc[pl * 64 + f0]);
            const float2 cs = *reinterpret_cast<const float2*>(&snc[pl * 64 + 32 + f0]);
            const f32x4 a = acc[nt][mt];
            float2 o1, o2;
            o1.x = a.x * cs.x - a.y * sn.x;              // col f0
            o1.y = a.z * cs.y - a.w * sn.y;              // col f0+1
            o2.x = a.x * sn.x + a.y * cs.x;              // col 32+f0
            o2.y = a.z * sn.y + a.w * cs.y;              // col 32+f0+1
            *reinterpret_cast<float2*>(op + f0)      = o1;
            *reinterpret_cast<float2*>(op + 32 + f0) = o2;
        }
    }
}

// ---------------------------------------------------------------------------
extern "C" void kernel_launch(void* const* d_in, const int* in_sizes, int n_in,
                              void* d_out, int out_size, void* d_ws, size_t ws_size,
                              hipStream_t stream)
{
    const float* x      = (const float*)d_in[0];
    const float* thetas = (const float*)d_in[1];
    const float* pairs  = (const float*)d_in[2];
    const float* tscale = (const float*)d_in[3];
    const float* M      = (const float*)d_in[4];
    const float* invf   = (const float*)d_in[5];
    float* out = (float*)d_out;
    unsigned short* Rt = (unsigned short*)d_ws;   // bf16 R^T, 8 KiB

    compose_R_kernel<<<1, 256, 0, stream>>>(thetas, pairs, tscale, M, Rt);

    const int n_hv   = in_sizes[0] / H_DIM;     // B*S*N_HEAD = 262144
    const int blocks = n_hv / 128;              // 2048
    rope_mfma_kernel<<<blocks, 256, 0, stream>>>(x, Rt, invf, out);
}

// Round 5
// 34.736 us; speedup vs baseline: 2.6237x; 1.2895x over previous
//
#include <hip/hip_runtime.h>
#include <hip/hip_bf16.h>
#include <math.h>

// Problem constants (fixed by the reference's setup_inputs)
#define N_STATE 1024
#define N_HEAD  16
#define H_DIM   64          // N_STATE / N_HEAD
#define NUM_ROT 8
#define SEQ     4096

typedef __attribute__((ext_vector_type(8))) short bf16x8;
typedef __attribute__((ext_vector_type(4))) float f32x4;

// float -> bf16 (round-to-nearest-even)
__device__ __forceinline__ unsigned short f2bf(float f) {
    union { float f; unsigned u; } v; v.f = f;
    unsigned r = v.u + 0x7fffu + ((v.u >> 16) & 1u);
    return (unsigned short)(r >> 16);
}

// ---------------------------------------------------------------------------
// Kernel 1: compose R = G_0 @ ... @ G_7 @ rotation_matrix, emit R^T in bf16
// (Rt[m][k] = R[k][m]) as the MFMA A operand. (M staged to LDS; round-2 fix.)
// ---------------------------------------------------------------------------
__global__ __launch_bounds__(256)
void compose_R_kernel(const float* __restrict__ thetas,
                      const float* __restrict__ pairs,
                      const float* __restrict__ theta_scale,
                      const float* __restrict__ M,
                      unsigned short* __restrict__ Rt)   // bf16 [64 m][64 k]
{
    __shared__ float R[H_DIM * H_DIM];
    __shared__ float Ms[H_DIM * H_DIM];
    __shared__ float th_s[NUM_ROT];
    __shared__ int   pr_s[2 * NUM_ROT];

    const int t = threadIdx.x;

    if (t < NUM_ROT)      th_s[t] = thetas[t] * theta_scale[0];
    if (t < 2 * NUM_ROT)  pr_s[t] = (int)pairs[t];

    {
        const float4* Mg = reinterpret_cast<const float4*>(M);
        float4* Ms4 = reinterpret_cast<float4*>(Ms);
        #pragma unroll
        for (int q = 0; q < 4; ++q)
            Ms4[t + q * 256] = Mg[t + q * 256];
    }
    {
        float4* R4 = reinterpret_cast<float4*>(R);
        #pragma unroll
        for (int q = 0; q < 4; ++q) {
            const int idx = t + q * 256;
            const int row = idx >> 4;
            const int c0  = (idx & 15) * 4;
            float4 v;
            v.x = (row == c0    ) ? 1.0f : 0.0f;
            v.y = (row == c0 + 1) ? 1.0f : 0.0f;
            v.z = (row == c0 + 2) ? 1.0f : 0.0f;
            v.w = (row == c0 + 3) ? 1.0f : 0.0f;
            R4[idx] = v;
        }
    }
    __syncthreads();

    for (int k = 0; k < NUM_ROT; ++k) {
        const int i = pr_s[2 * k];
        const int j = pr_s[2 * k + 1];
        float sth, cth;
        sincosf(th_s[k], &sth, &cth);
        if (t < H_DIM) {
            const float ri = R[t * H_DIM + i];
            const float rj = R[t * H_DIM + j];
            if (i == j) {
                R[t * H_DIM + i] = cth * ri;
            } else {
                R[t * H_DIM + i] =  cth * ri + sth * rj;
                R[t * H_DIM + j] = -sth * ri + cth * rj;
            }
        }
        __syncthreads();
    }

    // Rfinal = R @ Ms ; store transposed bf16
    const int r  = t >> 2;
    const int c0 = (t & 3) * 16;
    float acc[16];
    #pragma unroll
    for (int c = 0; c < 16; ++c) acc[c] = 0.0f;

    #pragma unroll 8
    for (int kk = 0; kk < H_DIM; ++kk) {
        const float a = R[r * H_DIM + kk];
        const float4* mrow = reinterpret_cast<const float4*>(&Ms[kk * H_DIM + c0]);
        #pragma unroll
        for (int c4 = 0; c4 < 4; ++c4) {
            const float4 m = mrow[c4];
            acc[c4 * 4 + 0] = fmaf(a, m.x, acc[c4 * 4 + 0]);
            acc[c4 * 4 + 1] = fmaf(a, m.y, acc[c4 * 4 + 1]);
            acc[c4 * 4 + 2] = fmaf(a, m.z, acc[c4 * 4 + 2]);
            acc[c4 * 4 + 3] = fmaf(a, m.w, acc[c4 * 4 + 3]);
        }
    }
    #pragma unroll
    for (int c = 0; c < 16; ++c)
        Rt[(c0 + c) * H_DIM + r] = f2bf(acc[c]);
}

// ---------------------------------------------------------------------------
// Kernel 2: MFMA main kernel, L1-traffic-minimized.
//  - Rt staged to LDS once per block (stride-72 shorts)
//  - x: wave-contiguous 1KiB loads -> bf16 -> wave-private LDS -> B-frags
//  - out: epilogue -> wave-private LDS (reused buffer) -> contiguous dwordx4
//  - one __syncthreads total; wave-private staging ordered by lgkmcnt only
// ---------------------------------------------------------------------------
#define HVPB 128
#define XS_STRIDE 72   // shorts per staged row (64 + 8 pad)
#define OS_STRIDE 68   // floats per staged out row (64 + 4 pad)

__global__ __launch_bounds__(256)
void rope_mfma_kernel(const float* __restrict__ x,
                      const unsigned short* __restrict__ Rt,  // bf16 [64][64]
                      const float* __restrict__ inv_freq,
                      float* __restrict__ out)
{
    __shared__ unsigned short Rs[H_DIM * XS_STRIDE];          // 9216 B
    __shared__ float snc[8 * 64];                             // 2048 B
    __shared__ __align__(16) float stage[4][16 * OS_STRIDE];  // 4 x 4352 B

    const int t   = threadIdx.x;
    const int w   = t >> 6;
    const int l   = t & 63;
    const int r16 = l & 15;
    const int q4  = l >> 4;
    const long long hv_base = (long long)blockIdx.x * HVPB;

    // --- stage Rt -> Rs: 1024 uint2 chunks, 16 chunks (of 4 shorts) per row ---
    {
        const uint2* Rg = reinterpret_cast<const uint2*>(Rt);
        #pragma unroll
        for (int i = 0; i < 4; ++i) {
            const int c  = t + i * 256;      // 0..1023
            const int m  = c >> 4;           // row 0..63    (FIX: was c>>3)
            const int k4 = c & 15;           // chunk in row (FIX: was c&7)
            *reinterpret_cast<uint2*>(&Rs[m * XS_STRIDE + k4 * 4]) = Rg[c];
        }
    }

    // --- sin/cos for this block's 8 positions ---
    {
        const int rl = t >> 5;
        const int f  = t & 31;
        const int pos = (int)(((hv_base >> 4) + rl) & (SEQ - 1));
        float sv, cv;
        sincosf((float)pos * inv_freq[f], &sv, &cv);
        snc[rl * 64 + f]      = sv;
        snc[rl * 64 + 32 + f] = cv;
    }
    __syncthreads();

    // --- A frags from Rs ---
    bf16x8 afr[4][2];
    #pragma unroll
    for (int mt = 0; mt < 4; ++mt)
        #pragma unroll
        for (int kh = 0; kh < 2; ++kh)
            afr[mt][kh] = *reinterpret_cast<const bf16x8*>(
                &Rs[(mt * 16 + r16) * XS_STRIDE + kh * 32 + q4 * 8]);

    unsigned short* xs = reinterpret_cast<unsigned short*>(&stage[w][0]);
    float*          os = &stage[w][0];

    #pragma unroll
    for (int nt = 0; nt < 2; ++nt) {
        const size_t row0 = (size_t)(hv_base + w * 32 + nt * 16);

        // --- load 16 rows (4KiB) wave-contiguous, cvt bf16, stage ---
        {
            const float4* xg = reinterpret_cast<const float4*>(x + row0 * H_DIM);
            #pragma unroll
            for (int i = 0; i < 4; ++i) {
                const int flat = i * 64 + l;     // float4 chunk 0..255
                const float4 v = xg[flat];
                const int row = flat >> 4;       // 0..15
                const int c4  = flat & 15;
                ushort4 b;
                b.x = f2bf(v.x); b.y = f2bf(v.y);
                b.z = f2bf(v.z); b.w = f2bf(v.w);
                *reinterpret_cast<ushort4*>(&xs[row * XS_STRIDE + c4 * 4]) = b;
            }
        }

        // --- B frags + MFMA (wave-private; lgkmcnt ordering) ---
        f32x4 acc[4];
        {
            bf16x8 b0 = *reinterpret_cast<const bf16x8*>(&xs[r16 * XS_STRIDE + 0 * 32 + q4 * 8]);
            bf16x8 b1 = *reinterpret_cast<const bf16x8*>(&xs[r16 * XS_STRIDE + 1 * 32 + q4 * 8]);
            #pragma unroll
            for (int mt = 0; mt < 4; ++mt) {
                f32x4 z = {0.0f, 0.0f, 0.0f, 0.0f};
                z = __builtin_amdgcn_mfma_f32_16x16x32_bf16(afr[mt][0], b0, z, 0, 0, 0);
                z = __builtin_amdgcn_mfma_f32_16x16x32_bf16(afr[mt][1], b1, z, 0, 0, 0);
                acc[mt] = z;
            }
        }

        // --- RoPE epilogue into wave-private LDS (reuses xs space) ---
        {
            const int pl = w * 2 + nt;
            #pragma unroll
            for (int mt = 0; mt < 4; ++mt) {
                const int f0 = mt * 8 + q4 * 2;          // even, 0..30
                const float2 sn = *reinterpret_cast<const float2*>(&snc[pl * 64 + f0]);
                const float2 cs = *reinterpret_cast<const float2*>(&snc[pl * 64 + 32 + f0]);
                const f32x4 a = acc[mt];
                float2 o1, o2;
                o1.x = a.x * cs.x - a.y * sn.x;          // col f0
                o1.y = a.z * cs.y - a.w * sn.y;          // col f0+1
                o2.x = a.x * sn.x + a.y * cs.x;          // col 32+f0
                o2.y = a.z * sn.y + a.w * cs.y;          // col 32+f0+1
                *reinterpret_cast<float2*>(&os[r16 * OS_STRIDE + f0])      = o1;
                *reinterpret_cast<float2*>(&os[r16 * OS_STRIDE + 32 + f0]) = o2;
            }
        }

        // --- read back row-major, store wave-contiguous 1KiB/instr ---
        {
            float4* og = reinterpret_cast<float4*>(out + row0 * H_DIM);
            #pragma unroll
            for (int i = 0; i < 4; ++i) {
                const int flat = i * 64 + l;
                const int row = flat >> 4;
                const int c4  = flat & 15;
                const float4 v = *reinterpret_cast<const float4*>(
                    &os[row * OS_STRIDE + c4 * 4]);
                og[flat] = v;
            }
        }
    }
}

// ---------------------------------------------------------------------------
extern "C" void kernel_launch(void* const* d_in, const int* in_sizes, int n_in,
                              void* d_out, int out_size, void* d_ws, size_t ws_size,
                              hipStream_t stream)
{
    const float* x      = (const float*)d_in[0];
    const float* thetas = (const float*)d_in[1];
    const float* pairs  = (const float*)d_in[2];
    const float* tscale = (const float*)d_in[3];
    const float* M      = (const float*)d_in[4];
    const float* invf   = (const float*)d_in[5];
    float* out = (float*)d_out;
    unsigned short* Rt = (unsigned short*)d_ws;   // bf16 R^T, 8 KiB

    compose_R_kernel<<<1, 256, 0, stream>>>(thetas, pairs, tscale, M, Rt);

    const int n_hv   = in_sizes[0] / H_DIM;     // B*S*N_HEAD = 262144
    const int blocks = n_hv / HVPB;              // 2048
    rope_mfma_kernel<<<blocks, 256, 0, stream>>>(x, Rt, invf, out);
}